// Round 2
// baseline (409.186 us; speedup 1.0000x reference)
//
#include <hip/hip_runtime.h>

#define N_PIX 50176
#define W_IMG 224
#define NT 98            // 32-row tiles per block column; 16 block-columns
#define ROWS 32

typedef __attribute__((ext_vector_type(8))) short s8v;   // 8 bf16
typedef __attribute__((ext_vector_type(4))) float f4v;

__device__ __forceinline__ unsigned short f2bf(float f) {
    __bf16 h = (__bf16)f;
    return __builtin_bit_cast(unsigned short, h);
}

// ---------------------------------------------------------------------------
// K0: Wk[col][k] (bf16, [128][192]): k<128 -> (w_obs2 @ w_ol1_top)^T
//                                    k>=128 -> w_ol1_bot^T  (em_loc extension)
//     wol2t[o][k] = w_ol2^T (bf16, [64][128])
//     bias_c[h2]  = b_ol1[h2] + b_obs2 @ w_ol1_top
// ---------------------------------------------------------------------------
__global__ void k0_weights(const float* __restrict__ w_obs2, const float* __restrict__ b_obs2,
                           const float* __restrict__ w_ol1, const float* __restrict__ b_ol1,
                           const float* __restrict__ w_ol2,
                           unsigned short* __restrict__ Wk,
                           unsigned short* __restrict__ wol2t,
                           float* __restrict__ bias_c) {
    int bid = blockIdx.x, t = threadIdx.x;
    if (bid < 64) {                       // 128x128 folded obs path
        int lin = bid * 256 + t;
        int n = lin >> 7, k = lin & 127;
        float s = 0.f;
        #pragma unroll
        for (int e = 0; e < 64; ++e) s = fmaf(w_obs2[k * 64 + e], w_ol1[e * 128 + n], s);
        Wk[n * 192 + k] = f2bf(s);
    } else if (bid < 96) {                // 128x64 loc extension
        int lin = (bid - 64) * 256 + t;
        int n = lin >> 6, k = lin & 63;
        Wk[n * 192 + 128 + k] = f2bf(w_ol1[(64 + k) * 128 + n]);
    } else if (bid < 128) {               // w_ol2 transpose
        int lin = (bid - 96) * 256 + t;
        int n = lin >> 7, k = lin & 127;
        wol2t[n * 128 + k] = f2bf(w_ol2[k * 64 + n]);
    } else {
        if (t < 128) {
            float s = b_ol1[t];
            #pragma unroll
            for (int e = 0; e < 64; ++e) s = fmaf(b_obs2[e], w_ol1[e * 128 + t], s);
            bias_c[t] = s;
        }
    }
}

// ---------------------------------------------------------------------------
// K1: em_loc (bf16, [N][64]) -- plain loc MLP, no fold.  4 threads/pixel.
// ---------------------------------------------------------------------------
__global__ __launch_bounds__(256) void k1_loc(
        const float* __restrict__ w_loc1, const float* __restrict__ b_loc1,
        const float* __restrict__ w_loc2, const float* __restrict__ b_loc2,
        unsigned short* __restrict__ emloc) {
    int gid = blockIdx.x * 256 + threadIdx.x;
    int n = gid >> 2, q = (gid & 3) * 16;
    int iy = n / W_IMG, ix = n % W_IMG;
    float y = -10.f + (20.f / 223.f) * (float)iy;
    float x = -10.f + (20.f / 223.f) * (float)ix;

    float em[16];
    #pragma unroll
    for (int e = 0; e < 16; ++e) em[e] = b_loc2[q + e];
    for (int h = 0; h < 128; ++h) {
        float hv = fmaf(y, w_loc1[h], fmaf(x, w_loc1[128 + h], b_loc1[h]));
        hv = fmaxf(hv, 0.f);
        const float* wr = w_loc2 + h * 64 + q;
        #pragma unroll
        for (int e = 0; e < 16; ++e) em[e] = fmaf(hv, wr[e], em[e]);
    }
    s8v v0, v1;
    #pragma unroll
    for (int e = 0; e < 8; ++e) { v0[e] = (short)f2bf(em[e]); v1[e] = (short)f2bf(em[8 + e]); }
    *(s8v*)(emloc + (size_t)n * 64 + q) = v0;
    *(s8v*)(emloc + (size_t)n * 64 + q + 8) = v1;
}

// ---------------------------------------------------------------------------
// K2: 3-stage software pipeline, 1 barrier/iter, 32-row tiles.
//   S1 (VALU): hidden_obs(tile i)   -> bufA[i&1]
//   S3 (MFMA): relu(bufA@Wk_ext + bias) (tile i-1) -> bufB[(i-1)&1], K=192
//   S4 (MFMA): softplus(bufB@w_ol2 + b_ol2) (tile i-2) -> spacc
// Waves: (ms = w&1) x (cq = w>>2? no: w>>1): 16 rows x 32 cols for S3,
//        16 rows x 16 o-cols (K=128 full) for S4.
// ---------------------------------------------------------------------------
#define SWZ(r, cb) (((r) << 8) + ((cb) ^ (((r) & 15) << 4)))

__global__ __launch_bounds__(512, 4) void k2_main(
        const float* __restrict__ images,
        const float* __restrict__ w_obs1, const float* __restrict__ b_obs1,
        const unsigned short* __restrict__ Wk, const float* __restrict__ biasc,
        const unsigned short* __restrict__ wol2t, const float* __restrict__ b_ol2,
        const unsigned short* __restrict__ emloc,
        float* __restrict__ part)          // [32][16][64]
{
    __shared__ char bufA[2][ROWS * 256];
    __shared__ char bufB[2][ROWS * 256];
    __shared__ float red[8][16];

    const int t = threadIdx.x;
    const int w = t >> 6, l = t & 63;
    const int l15 = l & 15, lg = l >> 4;
    const int ms = w & 1, cq = w >> 1;
    const int bx = blockIdx.x, b = blockIdx.y;
    const int base = bx * (NT * ROWS);
    const size_t imgb = (size_t)b * 3 * N_PIX;

    // S1 statics: this thread owns rows {2rp, 2rp+1} x h [h0, h0+4)
    const int rp = t >> 5;
    const int h0 = (t & 31) * 4;
    const f4v s1w0 = *(const f4v*)(w_obs1 + h0);
    const f4v s1w1 = *(const f4v*)(w_obs1 + 128 + h0);
    const f4v s1w2 = *(const f4v*)(w_obs1 + 256 + h0);
    const f4v s1b  = *(const f4v*)(b_obs1 + h0);

    // GEMM1 B fragments (persistent): 2 n-tiles x 6 k-steps
    s8v bw[2][6];
    #pragma unroll
    for (int nt = 0; nt < 2; ++nt) {
        int col = cq * 32 + nt * 16 + l15;
        #pragma unroll
        for (int ks = 0; ks < 6; ++ks)
            bw[nt][ks] = *(const s8v*)(Wk + col * 192 + ks * 32 + lg * 8);
    }
    // GEMM2 B fragments (persistent): 1 o-tile x 4 k-steps
    s8v w2f[4];
    {
        int o = cq * 16 + l15;
        #pragma unroll
        for (int ks = 0; ks < 4; ++ks)
            w2f[ks] = *(const s8v*)(wol2t + o * 128 + ks * 32 + lg * 8);
    }
    const float bias30 = biasc[cq * 32 + l15];
    const float bias31 = biasc[cq * 32 + 16 + l15];
    const float bias4  = b_ol2[cq * 16 + l15];

    float spacc = 0.f;
    const int arow = ms * 16 + l15;

    for (int i = 0; i <= NT + 1; ++i) {
        // ---- S1: hidden_obs(tile i) -> bufA[i&1]
        if (i < NT) {
            int n = base + i * ROWS + 2 * rp;
            const float* ip = images + imgb + n;
            float2 x0 = *(const float2*)(ip);
            float2 x1 = *(const float2*)(ip + N_PIX);
            float2 x2 = *(const float2*)(ip + 2 * N_PIX);
            char* bA = bufA[i & 1];
            #pragma unroll
            for (int rr = 0; rr < 2; ++rr) {
                float xa = rr ? x0.y : x0.x;
                float xb = rr ? x1.y : x1.x;
                float xc = rr ? x2.y : x2.x;
                unsigned int pk0, pk1;
                {
                    float h00 = fmaxf(fmaf(xa, s1w0[0], fmaf(xb, s1w1[0], fmaf(xc, s1w2[0], s1b[0]))), 0.f);
                    float h1 = fmaxf(fmaf(xa, s1w0[1], fmaf(xb, s1w1[1], fmaf(xc, s1w2[1], s1b[1]))), 0.f);
                    float h2 = fmaxf(fmaf(xa, s1w0[2], fmaf(xb, s1w1[2], fmaf(xc, s1w2[2], s1b[2]))), 0.f);
                    float h3 = fmaxf(fmaf(xa, s1w0[3], fmaf(xb, s1w1[3], fmaf(xc, s1w2[3], s1b[3]))), 0.f);
                    pk0 = (unsigned int)f2bf(h00) | ((unsigned int)f2bf(h1) << 16);
                    pk1 = (unsigned int)f2bf(h2) | ((unsigned int)f2bf(h3) << 16);
                }
                *(uint2*)(bA + SWZ(2 * rp + rr, h0 * 2)) = make_uint2(pk0, pk1);
            }
        }
        // ---- S3: relu(GEMM1 ext-K) (tile i-1) -> bufB[(i-1)&1]
        if (i >= 1 && i <= NT) {
            const char* bA = bufA[(i - 1) & 1];
            f4v acc0 = {0.f, 0.f, 0.f, 0.f}, acc1 = {0.f, 0.f, 0.f, 0.f};
            #pragma unroll
            for (int ks = 0; ks < 4; ++ks) {
                s8v a = *(const s8v*)(bA + SWZ(arow, ks * 64 + lg * 16));
                acc0 = __builtin_amdgcn_mfma_f32_16x16x32_bf16(a, bw[0][ks], acc0, 0, 0, 0);
                acc1 = __builtin_amdgcn_mfma_f32_16x16x32_bf16(a, bw[1][ks], acc1, 0, 0, 0);
            }
            {
                int n = base + (i - 1) * ROWS + arow;
                const unsigned short* ep = emloc + (size_t)n * 64 + lg * 8;
                s8v a4 = *(const s8v*)(ep);
                s8v a5 = *(const s8v*)(ep + 32);
                acc0 = __builtin_amdgcn_mfma_f32_16x16x32_bf16(a4, bw[0][4], acc0, 0, 0, 0);
                acc1 = __builtin_amdgcn_mfma_f32_16x16x32_bf16(a4, bw[1][4], acc1, 0, 0, 0);
                acc0 = __builtin_amdgcn_mfma_f32_16x16x32_bf16(a5, bw[0][5], acc0, 0, 0, 0);
                acc1 = __builtin_amdgcn_mfma_f32_16x16x32_bf16(a5, bw[1][5], acc1, 0, 0, 0);
            }
            char* bB = bufB[(i - 1) & 1];
            #pragma unroll
            for (int r = 0; r < 4; ++r) {
                int row = ms * 16 + lg * 4 + r;
                float v0 = fmaxf(acc0[r] + bias30, 0.f);
                float v1 = fmaxf(acc1[r] + bias31, 0.f);
                *(unsigned short*)(bB + SWZ(row, (cq * 32 + l15) * 2)) = f2bf(v0);
                *(unsigned short*)(bB + SWZ(row, (cq * 32 + 16 + l15) * 2)) = f2bf(v1);
            }
        }
        // ---- S4: softplus(GEMM2) (tile i-2) -> spacc
        if (i >= 2) {
            const char* bB = bufB[i & 1];
            f4v acc = {0.f, 0.f, 0.f, 0.f};
            #pragma unroll
            for (int ks = 0; ks < 4; ++ks) {
                s8v a = *(const s8v*)(bB + SWZ(arow, ks * 64 + lg * 16));
                acc = __builtin_amdgcn_mfma_f32_16x16x32_bf16(a, w2f[ks], acc, 0, 0, 0);
            }
            #pragma unroll
            for (int r = 0; r < 4; ++r) {
                float xv = acc[r] + bias4;
                spacc += fmaxf(xv, 0.f) + __logf(1.f + __expf(-fabsf(xv)));
            }
        }
        __syncthreads();
    }

    // column reduction: lane's o = cq*16 + l15; sum over lg, then ms pairs
    spacc += __shfl_xor(spacc, 16, 64);
    spacc += __shfl_xor(spacc, 32, 64);
    if (l < 16) red[w][l] = spacc;
    __syncthreads();
    if (t < 64) {
        int o = t;
        float s = red[(o >> 4) * 2][o & 15] + red[(o >> 4) * 2 + 1][o & 15];
        part[((size_t)b * 16 + bx) * 64 + o] = s;
    }
}

// ---------------------------------------------------------------------------
// K3: reduce partials + cls MLP (fp32)
// ---------------------------------------------------------------------------
__global__ __launch_bounds__(512) void k3_cls(
        const float* __restrict__ part,
        const float* __restrict__ w_cls1, const float* __restrict__ b_cls1,
        const float* __restrict__ w_cls2, const float* __restrict__ b_cls2,
        float* __restrict__ out) {
    __shared__ float es[32 * 64];
    __shared__ float hid[32 * 128];
    int t = threadIdx.x;
    #pragma unroll
    for (int q = 0; q < 4; ++q) {
        int idx = t + q * 512;                 // b*64+e
        float s = 0.f;
        #pragma unroll
        for (int x = 0; x < 16; ++x) s += part[(size_t)(idx >> 6) * 1024 + x * 64 + (idx & 63)];
        es[idx] = s;
    }
    __syncthreads();
    #pragma unroll
    for (int q = 0; q < 8; ++q) {
        int idx = t + q * 512;                 // b*128+h
        int bi = idx >> 7, h = idx & 127;
        float s = b_cls1[h];
        #pragma unroll
        for (int e = 0; e < 64; ++e) s = fmaf(es[bi * 64 + e], w_cls1[e * 128 + h], s);
        hid[idx] = fmaxf(s, 0.f);
    }
    __syncthreads();
    if (t < 320) {
        int bi = t / 10, o = t % 10;
        float s = b_cls2[o];
        for (int h = 0; h < 128; ++h) s = fmaf(hid[bi * 128 + h], w_cls2[h * 10 + o], s);
        out[t] = s;
    }
}

extern "C" void kernel_launch(void* const* d_in, const int* in_sizes, int n_in,
                              void* d_out, int out_size, void* d_ws, size_t ws_size,
                              hipStream_t stream) {
    (void)in_sizes; (void)n_in; (void)out_size; (void)ws_size;
    const float* images = (const float*)d_in[0];
    const float* w_obs1 = (const float*)d_in[1];
    const float* b_obs1 = (const float*)d_in[2];
    const float* w_obs2 = (const float*)d_in[3];
    const float* b_obs2 = (const float*)d_in[4];
    const float* w_loc1 = (const float*)d_in[5];
    const float* b_loc1 = (const float*)d_in[6];
    const float* w_loc2 = (const float*)d_in[7];
    const float* b_loc2 = (const float*)d_in[8];
    const float* w_ol1  = (const float*)d_in[9];
    const float* b_ol1  = (const float*)d_in[10];
    const float* w_ol2  = (const float*)d_in[11];
    const float* b_ol2  = (const float*)d_in[12];
    const float* w_cls1 = (const float*)d_in[13];
    const float* b_cls1 = (const float*)d_in[14];
    const float* w_cls2 = (const float*)d_in[15];
    const float* b_cls2 = (const float*)d_in[16];

    char* ws = (char*)d_ws;
    float* part           = (float*)(ws);                   // 32*16*64*4  = 131072
    float* biasc          = (float*)(ws + 131072);          // 128*4       = 512
    unsigned short* Wk    = (unsigned short*)(ws + 131584); // 128*192*2   = 49152
    unsigned short* wol2t = (unsigned short*)(ws + 180736); // 64*128*2    = 16384
    unsigned short* emloc = (unsigned short*)(ws + 197120); // 50176*64*2  = 6422528

    hipLaunchKernelGGL(k0_weights, dim3(129), dim3(256), 0, stream,
                       w_obs2, b_obs2, w_ol1, b_ol1, w_ol2, Wk, wol2t, biasc);
    hipLaunchKernelGGL(k1_loc, dim3(784), dim3(256), 0, stream,
                       w_loc1, b_loc1, w_loc2, b_loc2, emloc);
    hipLaunchKernelGGL(k2_main, dim3(16, 32), dim3(512), 0, stream,
                       images, w_obs1, b_obs1, Wk, biasc, wol2t, b_ol2, emloc, part);
    hipLaunchKernelGGL(k3_cls, dim3(1), dim3(512), 0, stream,
                       part, w_cls1, b_cls1, w_cls2, b_cls2, (float*)d_out);
}